// Round 2
// baseline (357.474 us; speedup 1.0000x reference)
//
#include <hip/hip_runtime.h>

typedef __attribute__((ext_vector_type(8))) __bf16 bf16x8;
typedef __attribute__((ext_vector_type(4))) float f32x4;

#define N_SAMP 256
#define DIM    2048
#define NCENT  32000
#define INV_T  14.285714285714285714f   // 1 / 0.07
#define NBLK   2000                      // 500 center-groups x 4 row-groups

// ---------------- kernel 1: row-normalize feats, emit bf16 ----------------
__global__ __launch_bounds__(256) void norm_kernel(const float* __restrict__ feats,
                                                   __bf16* __restrict__ fnorm) {
    int row = blockIdx.x;
    int tid = threadIdx.x;
    const float* src = feats + (size_t)row * DIM;
    float4 v0 = reinterpret_cast<const float4*>(src)[2 * tid];
    float4 v1 = reinterpret_cast<const float4*>(src)[2 * tid + 1];
    float ss = v0.x * v0.x + v0.y * v0.y + v0.z * v0.z + v0.w * v0.w
             + v1.x * v1.x + v1.y * v1.y + v1.z * v1.z + v1.w * v1.w;
    #pragma unroll
    for (int off = 1; off < 64; off <<= 1) ss += __shfl_xor(ss, off, 64);
    __shared__ float wsum[4];
    if ((tid & 63) == 0) wsum[tid >> 6] = ss;
    __syncthreads();
    float inv = 1.0f / sqrtf(wsum[0] + wsum[1] + wsum[2] + wsum[3]);
    bf16x8 o;
    o[0] = (__bf16)(v0.x * inv); o[1] = (__bf16)(v0.y * inv);
    o[2] = (__bf16)(v0.z * inv); o[3] = (__bf16)(v0.w * inv);
    o[4] = (__bf16)(v1.x * inv); o[5] = (__bf16)(v1.y * inv);
    o[6] = (__bf16)(v1.z * inv); o[7] = (__bf16)(v1.w * inv);
    *reinterpret_cast<bf16x8*>(fnorm + (size_t)row * DIM + tid * 8) = o;
}

// ------------- kernel 2: fused GEMM + masked reduce -------------
// 2000 blocks = 500 center-groups (64 centers) x 4 row-groups (64 rows).
// XCD swizzle groups the 4 row-group blocks sharing a center panel on one XCD.
// Block = 4 waves in a 2x2 arrangement; wave tile = 32 rows x 32 centers
// (acc = 2x2 16x16 frags = 16 VGPRs) -> fits 8 waves/SIMD.
__global__ __launch_bounds__(256, 8) void sims_kernel(
    const __bf16* __restrict__ fnorm, const float* __restrict__ centers,
    const int* __restrict__ labels, const int* __restrict__ camids,
    float* __restrict__ d_acc, float* __restrict__ d_own)
{
    __shared__ int s_lab[N_SAMP], s_cam[N_SAMP];
    int tid = threadIdx.x;
    s_lab[tid] = labels[tid];
    s_cam[tid] = camids[tid];
    __syncthreads();

    const int orig = blockIdx.x;
    const int swz  = (orig & 7) * (NBLK / 8) + (orig >> 3);  // bijective (2000 % 8 == 0)
    const int cg   = swz >> 2;   // 0..499 center group
    const int rg   = swz & 3;    // 0..3   row group

    const int wave = tid >> 6;
    const int lane = tid & 63;
    const int l15  = lane & 15;
    const int lhi  = lane >> 4;
    const int wrow = rg * 64 + (wave >> 1) * 32;
    const int wcol = cg * 64 + (wave & 1) * 32;

    f32x4 acc[2][2] = {};

    const __bf16* abase = fnorm   + (size_t)(wrow + l15) * DIM + lhi * 8;
    const float*  bbase = centers + (size_t)(wcol + l15) * DIM + lhi * 8;

    #pragma unroll 2
    for (int k0 = 0; k0 < DIM; k0 += 32) {
        bf16x8 afrag[2];
        float4 bx[2], by[2];
        #pragma unroll
        for (int mi = 0; mi < 2; ++mi)
            afrag[mi] = *reinterpret_cast<const bf16x8*>(abase + mi * 16 * DIM + k0);
        #pragma unroll
        for (int ni = 0; ni < 2; ++ni) {
            const float* p = bbase + (size_t)ni * 16 * DIM + k0;
            bx[ni] = *reinterpret_cast<const float4*>(p);
            by[ni] = *reinterpret_cast<const float4*>(p + 4);
        }
        #pragma unroll
        for (int ni = 0; ni < 2; ++ni) {
            bf16x8 b;
            b[0] = (__bf16)bx[ni].x; b[1] = (__bf16)bx[ni].y;
            b[2] = (__bf16)bx[ni].z; b[3] = (__bf16)bx[ni].w;
            b[4] = (__bf16)by[ni].x; b[5] = (__bf16)by[ni].y;
            b[6] = (__bf16)by[ni].z; b[7] = (__bf16)by[ni].w;
            #pragma unroll
            for (int mi = 0; mi < 2; ++mi)
                acc[mi][ni] = __builtin_amdgcn_mfma_f32_16x16x32_bf16(
                    afrag[mi], b, acc[mi][ni], 0, 0, 0);
        }
    }

    // epilogue: D elem (mi,ni,r) -> row wrow+mi*16+lhi*4+r, center wcol+ni*16+l15
    float* slot = d_acc + (orig & 7) * (2 * N_SAMP);
    #pragma unroll
    for (int mi = 0; mi < 2; ++mi) {
        #pragma unroll
        for (int r = 0; r < 4; ++r) {
            int i   = wrow + mi * 16 + lhi * 4 + r;
            int lab = s_lab[i], cam = s_cam[i];
            int oidx = lab * 8 + cam;
            float p_intra = 0.f, p_inter = 0.f;
            #pragma unroll
            for (int ni = 0; ni < 2; ++ni) {
                int c = wcol + ni * 16 + l15;
                float s = acc[mi][ni][r] * INV_T;
                float e = __expf(s);
                if ((l15 & 7) == cam) p_intra += e;      // c % 8 == cam
                bool own_lab = ((c >> 3) == lab);
                bool hard = (!own_lab) && (c < ((c < lab * 8) ? 50 : 58));
                if (own_lab || hard) p_inter += e;
                if (c == oidx) d_own[i] = s;
            }
            #pragma unroll
            for (int off = 1; off < 16; off <<= 1) {
                p_intra += __shfl_xor(p_intra, off, 64);
                p_inter += __shfl_xor(p_inter, off, 64);
            }
            if (l15 == 0) {
                atomicAdd(&slot[i], p_intra);
                atomicAdd(&slot[N_SAMP + i], p_inter);
            }
        }
    }
}

// ---------------- kernel 3: finalize (segment means + output) ----------------
__global__ __launch_bounds__(256) void finalize_kernel(
    const float* __restrict__ d_acc, const float* __restrict__ d_own,
    const int* __restrict__ labels, const int* __restrict__ camids,
    float* __restrict__ out, int out_size)
{
    __shared__ int s_lab[N_SAMP], s_cam[N_SAMP];
    __shared__ float wsum[8];
    int tid = threadIdx.x;
    s_lab[tid] = labels[tid];
    s_cam[tid] = camids[tid];
    __syncthreads();
    int myl = s_lab[tid], myc = s_cam[tid];
    int nl = 0, nc = 0;
    for (int j = 0; j < N_SAMP; ++j) {
        nl += (s_lab[j] == myl);
        nc += (s_cam[j] == myc);
    }
    float di = 0.f, dj = 0.f;
    #pragma unroll
    for (int s = 0; s < 8; ++s) {
        di += d_acc[s * 512 + tid];
        dj += d_acc[s * 512 + 256 + tid];
    }
    float own = d_own[tid];
    float li = own - logf(di);
    float lj = own - logf(dj);
    float a = li / (float)nc;   // sum_i loss_i / n_cam == sum over cams of per-cam mean
    float b = lj / (float)nl;
    #pragma unroll
    for (int off = 1; off < 64; off <<= 1) {
        a += __shfl_xor(a, off, 64);
        b += __shfl_xor(b, off, 64);
    }
    if ((tid & 63) == 0) { wsum[tid >> 6] = a; wsum[4 + (tid >> 6)] = b; }
    __syncthreads();
    if (tid == 0) {
        float sa = wsum[0] + wsum[1] + wsum[2] + wsum[3];
        float sb = wsum[4] + wsum[5] + wsum[6] + wsum[7];
        out[0] = -sa;
        if (out_size > 1) out[1] = -0.5f * sb;   // LAMDA = 0.5
    }
}

extern "C" void kernel_launch(void* const* d_in, const int* in_sizes, int n_in,
                              void* d_out, int out_size, void* d_ws, size_t ws_size,
                              hipStream_t stream) {
    const float* feats   = (const float*)d_in[0];
    const float* centers = (const float*)d_in[1];
    const int*   labels  = (const int*)d_in[2];
    const int*   camids  = (const int*)d_in[3];
    float* out = (float*)d_out;

    __bf16* fnorm  = (__bf16*)d_ws;
    float* d_acc = (float*)((char*)d_ws + (size_t)N_SAMP * DIM * sizeof(__bf16));
    float* d_own = d_acc + 8 * 2 * N_SAMP;

    hipMemsetAsync(d_acc, 0, 8 * 2 * N_SAMP * sizeof(float), stream);
    norm_kernel<<<N_SAMP, 256, 0, stream>>>(feats, fnorm);
    sims_kernel<<<NBLK, 256, 0, stream>>>(fnorm, centers, labels, camids, d_acc, d_own);
    finalize_kernel<<<1, 256, 0, stream>>>(d_acc, d_own, labels, camids, out, out_size);
}

// Round 3
// 184.167 us; speedup vs baseline: 1.9410x; 1.9410x over previous
//
#include <hip/hip_runtime.h>

typedef __attribute__((ext_vector_type(8))) __bf16 bf16x8;
typedef __attribute__((ext_vector_type(4))) __bf16 bf16x4;
typedef __attribute__((ext_vector_type(4))) float f32x4;

#define N_SAMP 256
#define DIM    2048
#define NCENT  32000
#define INV_T  14.285714285714285714f   // 1 / 0.07
#define NPANEL 500                       // blocks; 64 centers each, 2 chunks of 32 rows

// ---------------- kernel 1: row-normalize feats, emit bf16 ----------------
__global__ __launch_bounds__(256) void norm_kernel(const float* __restrict__ feats,
                                                   __bf16* __restrict__ fnorm) {
    int row = blockIdx.x;
    int tid = threadIdx.x;
    const float* src = feats + (size_t)row * DIM;
    float4 v0 = reinterpret_cast<const float4*>(src)[2 * tid];
    float4 v1 = reinterpret_cast<const float4*>(src)[2 * tid + 1];
    float ss = v0.x * v0.x + v0.y * v0.y + v0.z * v0.z + v0.w * v0.w
             + v1.x * v1.x + v1.y * v1.y + v1.z * v1.z + v1.w * v1.w;
    #pragma unroll
    for (int off = 1; off < 64; off <<= 1) ss += __shfl_xor(ss, off, 64);
    __shared__ float wsum[4];
    if ((tid & 63) == 0) wsum[tid >> 6] = ss;
    __syncthreads();
    float inv = 1.0f / sqrtf(wsum[0] + wsum[1] + wsum[2] + wsum[3]);
    bf16x8 o;
    o[0] = (__bf16)(v0.x * inv); o[1] = (__bf16)(v0.y * inv);
    o[2] = (__bf16)(v0.z * inv); o[3] = (__bf16)(v0.w * inv);
    o[4] = (__bf16)(v1.x * inv); o[5] = (__bf16)(v1.y * inv);
    o[6] = (__bf16)(v1.z * inv); o[7] = (__bf16)(v1.w * inv);
    *reinterpret_cast<bf16x8*>(fnorm + (size_t)row * DIM + tid * 8) = o;
}

// ------------- kernel 2: LDS-staged fused GEMM + masked reduce -------------
// 500 blocks x 512 threads (8 waves). Block owns 64 centers, processed as two
// 32-row chunks. Stage: read 32 full rows (256 KB, row-sequential 8 KB bursts),
// cvt f32->bf16, store to XOR-swizzled LDS (128 KiB). Compute: 8 waves, each
// 32 samples x 32 centers via 16x16x32 MFMA; A (fnorm, 1 MB bf16) from L2.
__global__ __launch_bounds__(512, 2) void sims_kernel(
    const __bf16* __restrict__ fnorm, const float* __restrict__ centers,
    const int* __restrict__ labels, const int* __restrict__ camids,
    float* __restrict__ d_acc, float* __restrict__ d_own)
{
    __shared__ __bf16 sB[32 * DIM];   // 128 KiB, rows swizzled by byte^((row&7)<<4)
    char* lds = (char*)sB;

    const int tid  = threadIdx.x;
    const int wave = tid >> 6;
    const int lane = tid & 63;
    const int l15  = lane & 15;
    const int lhi  = lane >> 4;
    const int wrow = wave * 32;               // this wave's 32 sample rows
    const int cbase = blockIdx.x * 64;        // panel's first center
    const int swz   = (l15 & 7) << 4;         // LDS read swizzle (rows r and r+8 share)
    const int bb0   = l15 * 4096 + lhi * 16;  // frag ni adds 16*4096
    float* slot = d_acc + (blockIdx.x & 7) * 512;

    for (int ch = 0; ch < 2; ++ch) {
        if (ch) __syncthreads();              // all waves done reading previous chunk

        // ---- stage: 32 rows, each read as one contiguous 8 KB burst ----
        const float* src = centers + (size_t)(cbase + ch * 32) * DIM;
        {
            float4 v[2][8];
            #pragma unroll
            for (int j = 0; j < 8; ++j)
                v[0][j] = *reinterpret_cast<const float4*>(src + (size_t)j * DIM + tid * 4);
            for (int b = 0; b < 4; ++b) {
                if (b < 3) {
                    #pragma unroll
                    for (int j = 0; j < 8; ++j)
                        v[(b + 1) & 1][j] = *reinterpret_cast<const float4*>(
                            src + (size_t)((b + 1) * 8 + j) * DIM + tid * 4);
                }
                #pragma unroll
                for (int j = 0; j < 8; ++j) {
                    int row = b * 8 + j;
                    float4 x = v[b & 1][j];
                    bf16x4 o;
                    o[0] = (__bf16)x.x; o[1] = (__bf16)x.y;
                    o[2] = (__bf16)x.z; o[3] = (__bf16)x.w;
                    *reinterpret_cast<bf16x4*>(
                        lds + ((row * 4096 + tid * 8) ^ ((row & 7) << 4))) = o;
                }
            }
        }
        __syncthreads();

        // ---- GEMM: 256 samples x 32 centers, K = 2048 ----
        f32x4 acc[2][2] = {};
        const __bf16* a0 = fnorm + (size_t)(wrow + l15) * DIM + lhi * 8;
        #pragma unroll 4
        for (int k0 = 0; k0 < DIM; k0 += 32) {
            bf16x8 af[2], bf[2];
            #pragma unroll
            for (int mi = 0; mi < 2; ++mi)
                af[mi] = *reinterpret_cast<const bf16x8*>(a0 + mi * 16 * DIM + k0);
            #pragma unroll
            for (int ni = 0; ni < 2; ++ni) {
                int addr = (bb0 + ni * 65536 + k0 * 2) ^ swz;
                bf[ni] = *reinterpret_cast<const bf16x8*>(lds + addr);
            }
            #pragma unroll
            for (int mi = 0; mi < 2; ++mi)
                #pragma unroll
                for (int ni = 0; ni < 2; ++ni)
                    acc[mi][ni] = __builtin_amdgcn_mfma_f32_16x16x32_bf16(
                        af[mi], bf[ni], acc[mi][ni], 0, 0, 0);
        }

        // ---- epilogue: exp + masks + per-sample partial denominators ----
        #pragma unroll
        for (int mi = 0; mi < 2; ++mi) {
            #pragma unroll
            for (int r = 0; r < 4; ++r) {
                int i   = wrow + mi * 16 + lhi * 4 + r;
                int lab = labels[i], cam = camids[i];
                int oidx = lab * 8 + cam;
                float p_intra = 0.f, p_inter = 0.f;
                #pragma unroll
                for (int ni = 0; ni < 2; ++ni) {
                    int c = cbase + ch * 32 + ni * 16 + l15;
                    float s = acc[mi][ni][r] * INV_T;
                    float e = __expf(s);
                    if ((l15 & 7) == cam) p_intra += e;        // c % 8 == cam
                    bool own_lab = ((c >> 3) == lab);
                    bool hard = (!own_lab) && (c < ((c < lab * 8) ? 50 : 58));
                    if (own_lab || hard) p_inter += e;
                    if (c == oidx) d_own[i] = s;
                }
                #pragma unroll
                for (int off = 1; off < 16; off <<= 1) {
                    p_intra += __shfl_xor(p_intra, off, 64);
                    p_inter += __shfl_xor(p_inter, off, 64);
                }
                if (l15 == 0) {
                    atomicAdd(&slot[i], p_intra);
                    atomicAdd(&slot[N_SAMP + i], p_inter);
                }
            }
        }
    }
}

// ---------------- kernel 3: finalize (segment means + output) ----------------
__global__ __launch_bounds__(256) void finalize_kernel(
    const float* __restrict__ d_acc, const float* __restrict__ d_own,
    const int* __restrict__ labels, const int* __restrict__ camids,
    float* __restrict__ out, int out_size)
{
    __shared__ int s_lab[N_SAMP], s_cam[N_SAMP];
    __shared__ float wsum[8];
    int tid = threadIdx.x;
    s_lab[tid] = labels[tid];
    s_cam[tid] = camids[tid];
    __syncthreads();
    int myl = s_lab[tid], myc = s_cam[tid];
    int nl = 0, nc = 0;
    for (int j = 0; j < N_SAMP; ++j) {
        nl += (s_lab[j] == myl);
        nc += (s_cam[j] == myc);
    }
    float di = 0.f, dj = 0.f;
    #pragma unroll
    for (int s = 0; s < 8; ++s) {
        di += d_acc[s * 512 + tid];
        dj += d_acc[s * 512 + 256 + tid];
    }
    float own = d_own[tid];
    float li = own - logf(di);
    float lj = own - logf(dj);
    float a = li / (float)nc;   // sum_i loss_i / n_cam == sum over cams of per-cam mean
    float b = lj / (float)nl;
    #pragma unroll
    for (int off = 1; off < 64; off <<= 1) {
        a += __shfl_xor(a, off, 64);
        b += __shfl_xor(b, off, 64);
    }
    if ((tid & 63) == 0) { wsum[tid >> 6] = a; wsum[4 + (tid >> 6)] = b; }
    __syncthreads();
    if (tid == 0) {
        float sa = wsum[0] + wsum[1] + wsum[2] + wsum[3];
        float sb = wsum[4] + wsum[5] + wsum[6] + wsum[7];
        out[0] = -sa;
        if (out_size > 1) out[1] = -0.5f * sb;   // LAMDA = 0.5
    }
}

extern "C" void kernel_launch(void* const* d_in, const int* in_sizes, int n_in,
                              void* d_out, int out_size, void* d_ws, size_t ws_size,
                              hipStream_t stream) {
    const float* feats   = (const float*)d_in[0];
    const float* centers = (const float*)d_in[1];
    const int*   labels  = (const int*)d_in[2];
    const int*   camids  = (const int*)d_in[3];
    float* out = (float*)d_out;

    __bf16* fnorm = (__bf16*)d_ws;
    float* d_acc  = (float*)((char*)d_ws + (size_t)N_SAMP * DIM * sizeof(__bf16));
    float* d_own  = d_acc + 8 * 2 * N_SAMP;

    hipMemsetAsync(d_acc, 0, 8 * 2 * N_SAMP * sizeof(float), stream);
    norm_kernel<<<N_SAMP, 256, 0, stream>>>(feats, fnorm);
    sims_kernel<<<NPANEL, 512, 0, stream>>>(fnorm, centers, labels, camids, d_acc, d_own);
    finalize_kernel<<<1, 256, 0, stream>>>(d_acc, d_own, labels, camids, out, out_size);
}

// Round 4
// 99.833 us; speedup vs baseline: 3.5807x; 1.8447x over previous
//
#include <hip/hip_runtime.h>

typedef __attribute__((ext_vector_type(8))) __bf16 bf16x8;
typedef __attribute__((ext_vector_type(4))) __bf16 bf16x4;
typedef __attribute__((ext_vector_type(4))) float f32x4;

#define N_SAMP 256
#define DIM    2048
#define NCENT  32000
#define INV_T  14.285714285714285714f   // 1 / 0.07
#define NWG    500                       // 250 n-tiles x 2 m-tiles

// ---------------- kernel 1: row-normalize feats, emit bf16 ----------------
__global__ __launch_bounds__(256) void norm_kernel(const float* __restrict__ feats,
                                                   __bf16* __restrict__ fnorm) {
    int row = blockIdx.x;
    int tid = threadIdx.x;
    const float* src = feats + (size_t)row * DIM;
    float4 v0 = reinterpret_cast<const float4*>(src)[2 * tid];
    float4 v1 = reinterpret_cast<const float4*>(src)[2 * tid + 1];
    float ss = v0.x * v0.x + v0.y * v0.y + v0.z * v0.z + v0.w * v0.w
             + v1.x * v1.x + v1.y * v1.y + v1.z * v1.z + v1.w * v1.w;
    #pragma unroll
    for (int off = 1; off < 64; off <<= 1) ss += __shfl_xor(ss, off, 64);
    __shared__ float wsum[4];
    if ((tid & 63) == 0) wsum[tid >> 6] = ss;
    __syncthreads();
    float inv = 1.0f / sqrtf(wsum[0] + wsum[1] + wsum[2] + wsum[3]);
    bf16x8 o;
    o[0] = (__bf16)(v0.x * inv); o[1] = (__bf16)(v0.y * inv);
    o[2] = (__bf16)(v0.z * inv); o[3] = (__bf16)(v0.w * inv);
    o[4] = (__bf16)(v1.x * inv); o[5] = (__bf16)(v1.y * inv);
    o[6] = (__bf16)(v1.z * inv); o[7] = (__bf16)(v1.w * inv);
    *reinterpret_cast<bf16x8*>(fnorm + (size_t)row * DIM + tid * 8) = o;
}

// ------------- kernel 2: pipelined 128x128 GEMM + masked reduce -------------
// 500 blocks x 512 threads (8 waves, 2 m-halves x 4 n-strips; wave = 64x32).
// BK=32, both operands staged regs->swizzled LDS, double-buffered, loads for
// step t+1 issued before compute(t) so HBM latency hides under MFMA.
__global__ __launch_bounds__(512, 2) void sims_kernel(
    const __bf16* __restrict__ fnorm, const float* __restrict__ centers,
    const int* __restrict__ labels, const int* __restrict__ camids,
    float* __restrict__ d_acc, float* __restrict__ d_own)
{
    __shared__ __align__(16) uint2 sA[2][1024];  // 128 rows x 32 bf16 (64 B), swizzled
    __shared__ __align__(16) uint2 sB[2][1024];

    const int tid  = threadIdx.x;
    const int wave = tid >> 6;
    const int lane = tid & 63;
    const int l15  = lane & 15;
    const int lhi  = lane >> 4;

    // bijective XCD swizzle (nwg=500: q=62, r=4); pairs (n, m=0/1) adjacent per XCD
    const int d   = blockIdx.x;
    const int xcd = d & 7, loc = d >> 3;
    const int lid = (xcd < 4 ? xcd * 63 : 252 + (xcd - 4) * 62) + loc;
    const int nb  = lid >> 1;     // 0..249 center tile (128 centers)
    const int mb  = lid & 1;      // 0..1   sample tile (128 samples)

    const int wr = (wave >> 2) * 64;   // wave rows within tile
    const int wc = (wave & 3) * 32;    // wave cols within tile

    f32x4 acc[4][2] = {};

    float4 vB[2];
    uint4  vA;

    const float4* bsrc = reinterpret_cast<const float4*>(centers);
    const uint4*  asrc = reinterpret_cast<const uint4*>(fnorm);

    // ---- staging helpers ----
    auto stage_load = [&](int step) {
        #pragma unroll
        for (int j = 0; j < 2; ++j) {
            int f = j * 512 + tid;           // 1024 float4 = 128 rows x 8
            int row = f >> 3, pos = f & 7;
            vB[j] = bsrc[(size_t)(nb * 128 + row) * 512 + step * 8 + pos];
        }
        {
            int row = tid >> 2, pos = tid & 3;  // 512 uint4 = 128 rows x 4
            vA = asrc[(size_t)(mb * 128 + row) * 256 + step * 4 + pos];
        }
    };
    auto stage_write = [&](int b) {
        #pragma unroll
        for (int j = 0; j < 2; ++j) {
            int f = j * 512 + tid;
            int row = f >> 3, pos = f & 7;
            int lin = row * 64 + pos * 8;
            int adr = lin ^ (((lin >> 7) & 7) << 4);
            bf16x4 o;
            o[0] = (__bf16)vB[j].x; o[1] = (__bf16)vB[j].y;
            o[2] = (__bf16)vB[j].z; o[3] = (__bf16)vB[j].w;
            sB[b][adr >> 3] = __builtin_bit_cast(uint2, o);
        }
        {
            int row = tid >> 2, pos = tid & 3;
            int lin = row * 64 + pos * 16;
            int adr = lin ^ (((lin >> 7) & 7) << 4);
            sA[b][adr >> 3]     = make_uint2(vA.x, vA.y);
            sA[b][(adr >> 3)+1] = make_uint2(vA.z, vA.w);
        }
    };
    auto compute = [&](int b) {
        bf16x8 af[4], bf[2];
        #pragma unroll
        for (int mi = 0; mi < 4; ++mi) {
            int lin = (wr + mi * 16 + l15) * 64 + lhi * 16;
            int adr = lin ^ (((lin >> 7) & 7) << 4);
            af[mi] = *reinterpret_cast<const bf16x8*>(&sA[b][adr >> 3]);
        }
        #pragma unroll
        for (int ni = 0; ni < 2; ++ni) {
            int lin = (wc + ni * 16 + l15) * 64 + lhi * 16;
            int adr = lin ^ (((lin >> 7) & 7) << 4);
            bf[ni] = *reinterpret_cast<const bf16x8*>(&sB[b][adr >> 3]);
        }
        #pragma unroll
        for (int mi = 0; mi < 4; ++mi)
            #pragma unroll
            for (int ni = 0; ni < 2; ++ni)
                acc[mi][ni] = __builtin_amdgcn_mfma_f32_16x16x32_bf16(
                    af[mi], bf[ni], acc[mi][ni], 0, 0, 0);
    };

    // ---- pipelined main loop: 64 K-steps ----
    stage_load(0);
    stage_write(0);
    __syncthreads();
    int cur = 0;
    for (int step = 0; step < 64; ++step) {
        if (step < 63) stage_load(step + 1);   // loads in flight during compute
        compute(cur);
        if (step < 63) { stage_write(cur ^ 1); cur ^= 1; }
        __syncthreads();
    }

    // ---- epilogue: exp + masks + per-sample partial denominators ----
    float* slot = d_acc + (d & 7) * 512;
    #pragma unroll
    for (int mi = 0; mi < 4; ++mi) {
        #pragma unroll
        for (int r = 0; r < 4; ++r) {
            int i   = mb * 128 + wr + mi * 16 + lhi * 4 + r;
            int lab = labels[i], cam = camids[i];
            int oidx = lab * 8 + cam;
            float pi = 0.f, pj = 0.f;
            #pragma unroll
            for (int ni = 0; ni < 2; ++ni) {
                int c = nb * 128 + wc + ni * 16 + l15;
                float s = acc[mi][ni][r] * INV_T;
                float e = __expf(s);
                if ((l15 & 7) == cam) pi += e;          // c % 8 == cam
                bool ol = ((c >> 3) == lab);
                bool hard = (!ol) && (c < ((c < lab * 8) ? 50 : 58));
                if (ol || hard) pj += e;
                if (c == oidx) d_own[i] = s;
            }
            #pragma unroll
            for (int off = 1; off < 16; off <<= 1) {
                pi += __shfl_xor(pi, off, 64);
                pj += __shfl_xor(pj, off, 64);
            }
            if (l15 == 0) {
                atomicAdd(&slot[i], pi);
                atomicAdd(&slot[N_SAMP + i], pj);
            }
        }
    }
}

// ---------------- kernel 3: finalize (segment means + output) ----------------
__global__ __launch_bounds__(256) void finalize_kernel(
    const float* __restrict__ d_acc, const float* __restrict__ d_own,
    const int* __restrict__ labels, const int* __restrict__ camids,
    float* __restrict__ out, int out_size)
{
    __shared__ int s_lab[N_SAMP], s_cam[N_SAMP];
    __shared__ float wsum[8];
    int tid = threadIdx.x;
    s_lab[tid] = labels[tid];
    s_cam[tid] = camids[tid];
    __syncthreads();
    int myl = s_lab[tid], myc = s_cam[tid];
    int nl = 0, nc = 0;
    for (int j = 0; j < N_SAMP; ++j) {
        nl += (s_lab[j] == myl);
        nc += (s_cam[j] == myc);
    }
    float di = 0.f, dj = 0.f;
    #pragma unroll
    for (int s = 0; s < 8; ++s) {
        di += d_acc[s * 512 + tid];
        dj += d_acc[s * 512 + 256 + tid];
    }
    float own = d_own[tid];
    float li = own - logf(di);
    float lj = own - logf(dj);
    float a = li / (float)nc;   // sum_i loss_i / n_cam == sum over cams of per-cam mean
    float b = lj / (float)nl;
    #pragma unroll
    for (int off = 1; off < 64; off <<= 1) {
        a += __shfl_xor(a, off, 64);
        b += __shfl_xor(b, off, 64);
    }
    if ((tid & 63) == 0) { wsum[tid >> 6] = a; wsum[4 + (tid >> 6)] = b; }
    __syncthreads();
    if (tid == 0) {
        float sa = wsum[0] + wsum[1] + wsum[2] + wsum[3];
        float sb = wsum[4] + wsum[5] + wsum[6] + wsum[7];
        out[0] = -sa;
        if (out_size > 1) out[1] = -0.5f * sb;   // LAMDA = 0.5
    }
}

extern "C" void kernel_launch(void* const* d_in, const int* in_sizes, int n_in,
                              void* d_out, int out_size, void* d_ws, size_t ws_size,
                              hipStream_t stream) {
    const float* feats   = (const float*)d_in[0];
    const float* centers = (const float*)d_in[1];
    const int*   labels  = (const int*)d_in[2];
    const int*   camids  = (const int*)d_in[3];
    float* out = (float*)d_out;

    __bf16* fnorm = (__bf16*)d_ws;
    float* d_acc  = (float*)((char*)d_ws + (size_t)N_SAMP * DIM * sizeof(__bf16));
    float* d_own  = d_acc + 8 * 2 * N_SAMP;

    hipMemsetAsync(d_acc, 0, 8 * 2 * N_SAMP * sizeof(float), stream);
    norm_kernel<<<N_SAMP, 256, 0, stream>>>(feats, fnorm);
    sims_kernel<<<NWG, 512, 0, stream>>>(fnorm, centers, labels, camids, d_acc, d_own);
    finalize_kernel<<<1, 256, 0, stream>>>(d_acc, d_own, labels, camids, out, out_size);
}

// Round 5
// 89.608 us; speedup vs baseline: 3.9893x; 1.1141x over previous
//
#include <hip/hip_runtime.h>

typedef __attribute__((ext_vector_type(8))) __bf16 bf16x8;
typedef __attribute__((ext_vector_type(4))) __bf16 bf16x4;
typedef __attribute__((ext_vector_type(4))) float f32x4;

#define N_SAMP 256
#define DIM    2048
#define NCENT  32000
#define INV_T  14.285714285714285714f   // 1 / 0.07
#define NWG    500                       // 250 n-tiles x 2 m-tiles

// ---------------- kernel 1: row-normalize feats -> bf16; also zero d_acc ----------------
__global__ __launch_bounds__(256) void norm_kernel(const float* __restrict__ feats,
                                                   __bf16* __restrict__ fnorm,
                                                   float* __restrict__ d_acc) {
    int row = blockIdx.x;
    int tid = threadIdx.x;
    if (row < 16) d_acc[row * 256 + tid] = 0.f;   // zero 8 slots x 512 floats
    const float* src = feats + (size_t)row * DIM;
    float4 v0 = reinterpret_cast<const float4*>(src)[2 * tid];
    float4 v1 = reinterpret_cast<const float4*>(src)[2 * tid + 1];
    float ss = v0.x * v0.x + v0.y * v0.y + v0.z * v0.z + v0.w * v0.w
             + v1.x * v1.x + v1.y * v1.y + v1.z * v1.z + v1.w * v1.w;
    #pragma unroll
    for (int off = 1; off < 64; off <<= 1) ss += __shfl_xor(ss, off, 64);
    __shared__ float wsum[4];
    if ((tid & 63) == 0) wsum[tid >> 6] = ss;
    __syncthreads();
    float inv = 1.0f / sqrtf(wsum[0] + wsum[1] + wsum[2] + wsum[3]);
    bf16x8 o;
    o[0] = (__bf16)(v0.x * inv); o[1] = (__bf16)(v0.y * inv);
    o[2] = (__bf16)(v0.z * inv); o[3] = (__bf16)(v0.w * inv);
    o[4] = (__bf16)(v1.x * inv); o[5] = (__bf16)(v1.y * inv);
    o[6] = (__bf16)(v1.z * inv); o[7] = (__bf16)(v1.w * inv);
    *reinterpret_cast<bf16x8*>(fnorm + (size_t)row * DIM + tid * 8) = o;
}

// ------------- kernel 2: pipelined 128x128 GEMM, counted-vmcnt barriers -------------
// 500 blocks x 512 threads. BK=32, depth-2 reg pipeline, raw s_barrier with
// lgkmcnt(0)-only drain so global loads stay in flight across barriers.
__global__ __launch_bounds__(512, 4) void sims_kernel(
    const __bf16* __restrict__ fnorm, const float* __restrict__ centers,
    const int* __restrict__ labels, const int* __restrict__ camids,
    float* __restrict__ d_acc, float* __restrict__ d_own)
{
    __shared__ __align__(16) char sA[2][8192];   // 128 rows x 32 bf16 (64 B), swizzled
    __shared__ __align__(16) char sB[2][8192];

    const int tid  = threadIdx.x;
    const int wave = tid >> 6;
    const int lane = tid & 63;
    const int l15  = lane & 15;
    const int lhi  = lane >> 4;

    // bijective XCD swizzle (nwg=500: q=62, r=4); pairs (n, m=0/1) adjacent per XCD
    const int d   = blockIdx.x;
    const int xcd = d & 7, loc = d >> 3;
    const int lid = (xcd < 4 ? xcd * 63 : 252 + (xcd - 4) * 62) + loc;
    const int nb  = lid >> 1;     // 0..249 center tile (128 centers)
    const int mb  = lid & 1;      // 0..1   sample tile (128 samples)

    const int wr = (wave >> 2) * 64;   // wave rows within tile
    const int wc = (wave & 3) * 32;    // wave cols within tile

    f32x4 acc[4][2] = {};

    const float4* bsrc = reinterpret_cast<const float4*>(centers);
    const uint4*  asrc = reinterpret_cast<const uint4*>(fnorm);

    // B: f = j*512+tid (j=0,1): row=f>>3 (0..127), pos=f&7 (8 float4 = 32 f32/row)
    // A: row=tid>>2 (0..127), pos=tid&3 (4 uint4 = 32 bf16/row)
    auto issue = [&](int step, float4& b0, float4& b1, uint4& a) {
        int r0 = tid >> 3, p0 = tid & 7;
        b0 = bsrc[(size_t)(nb * 128 + r0) * 512 + step * 8 + p0];
        int r1 = (512 + tid) >> 3, p1 = tid & 7;
        b1 = bsrc[(size_t)(nb * 128 + r1) * 512 + step * 8 + p1];
        int ra = tid >> 2, pa = tid & 3;
        a = asrc[(size_t)(mb * 128 + ra) * 256 + step * 4 + pa];
    };
    auto wrbuf = [&](int b, const float4& b0, const float4& b1, const uint4& a) {
        #pragma unroll
        for (int j = 0; j < 2; ++j) {
            const float4& v = j ? b1 : b0;
            int row = (j * 512 + tid) >> 3, pos = tid & 7;
            int adr = (row * 64 + pos * 8) ^ ((row & 7) << 4);
            bf16x4 o;
            o[0] = (__bf16)v.x; o[1] = (__bf16)v.y;
            o[2] = (__bf16)v.z; o[3] = (__bf16)v.w;
            *reinterpret_cast<uint2*>(&sB[b][adr]) = __builtin_bit_cast(uint2, o);
        }
        {
            int row = tid >> 2, pos = tid & 3;
            int adr = (row * 64 + pos * 16) ^ ((row & 7) << 4);
            *reinterpret_cast<uint4*>(&sA[b][adr]) = a;
        }
    };
    auto compute = [&](int b) {
        bf16x8 af[4], bf[2];
        #pragma unroll
        for (int mi = 0; mi < 4; ++mi) {
            int row = wr + mi * 16 + l15;
            int adr = (row * 64 + lhi * 16) ^ ((row & 7) << 4);
            af[mi] = *reinterpret_cast<const bf16x8*>(&sA[b][adr]);
        }
        #pragma unroll
        for (int ni = 0; ni < 2; ++ni) {
            int row = wc + ni * 16 + l15;
            int adr = (row * 64 + lhi * 16) ^ ((row & 7) << 4);
            bf[ni] = *reinterpret_cast<const bf16x8*>(&sB[b][adr]);
        }
        #pragma unroll
        for (int mi = 0; mi < 4; ++mi)
            #pragma unroll
            for (int ni = 0; ni < 2; ++ni)
                acc[mi][ni] = __builtin_amdgcn_mfma_f32_16x16x32_bf16(
                    af[mi], bf[ni], acc[mi][ni], 0, 0, 0);
    };
    #define BAR() do { asm volatile("s_waitcnt lgkmcnt(0)" ::: "memory"); \
                       __builtin_amdgcn_s_barrier(); } while (0)

    float4 b0A, b1A; uint4 aA;     // set A
    float4 b0B, b1B; uint4 aB;     // set B

    issue(0, b0A, b1A, aA);
    issue(1, b0B, b1B, aB);
    wrbuf(0, b0A, b1A, aA);
    BAR();
    for (int t = 0; t < 64; t += 2) {
        if (t + 2 < 64) issue(t + 2, b0A, b1A, aA);
        compute(0);
        wrbuf(1, b0B, b1B, aB);          // vmcnt waits on set B only; set A in flight
        BAR();
        if (t + 3 < 64) issue(t + 3, b0B, b1B, aB);
        compute(1);
        if (t + 2 < 64) {
            wrbuf(0, b0A, b1A, aA);
            BAR();
        }
    }

    // ---- epilogue: exp + masks + per-sample partial denominators ----
    float* slot = d_acc + (d & 7) * 512;
    #pragma unroll
    for (int mi = 0; mi < 4; ++mi) {
        #pragma unroll
        for (int r = 0; r < 4; ++r) {
            int i   = mb * 128 + wr + mi * 16 + lhi * 4 + r;
            int lab = labels[i], cam = camids[i];
            int oidx = lab * 8 + cam;
            float pi = 0.f, pj = 0.f;
            #pragma unroll
            for (int ni = 0; ni < 2; ++ni) {
                int c = nb * 128 + wc + ni * 16 + l15;
                float s = acc[mi][ni][r] * INV_T;
                float e = __expf(s);
                if ((l15 & 7) == cam) pi += e;          // c % 8 == cam
                bool ol = ((c >> 3) == lab);
                bool hard = (!ol) && (c < ((c < lab * 8) ? 50 : 58));
                if (ol || hard) pj += e;
                if (c == oidx) d_own[i] = s;
            }
            #pragma unroll
            for (int off = 1; off < 16; off <<= 1) {
                pi += __shfl_xor(pi, off, 64);
                pj += __shfl_xor(pj, off, 64);
            }
            if (l15 == 0) {
                atomicAdd(&slot[i], pi);
                atomicAdd(&slot[N_SAMP + i], pj);
            }
        }
    }
}

// ---------------- kernel 3: finalize (segment means + output) ----------------
__global__ __launch_bounds__(256) void finalize_kernel(
    const float* __restrict__ d_acc, const float* __restrict__ d_own,
    const int* __restrict__ labels, const int* __restrict__ camids,
    float* __restrict__ out, int out_size)
{
    __shared__ int s_lab[N_SAMP], s_cam[N_SAMP];
    __shared__ float wsum[8];
    int tid = threadIdx.x;
    s_lab[tid] = labels[tid];
    s_cam[tid] = camids[tid];
    __syncthreads();
    int myl = s_lab[tid], myc = s_cam[tid];
    int nl = 0, nc = 0;
    for (int j = 0; j < N_SAMP; ++j) {
        nl += (s_lab[j] == myl);
        nc += (s_cam[j] == myc);
    }
    float di = 0.f, dj = 0.f;
    #pragma unroll
    for (int s = 0; s < 8; ++s) {
        di += d_acc[s * 512 + tid];
        dj += d_acc[s * 512 + 256 + tid];
    }
    float own = d_own[tid];
    float li = own - logf(di);
    float lj = own - logf(dj);
    float a = li / (float)nc;   // sum_i loss_i / n_cam == sum over cams of per-cam mean
    float b = lj / (float)nl;
    #pragma unroll
    for (int off = 1; off < 64; off <<= 1) {
        a += __shfl_xor(a, off, 64);
        b += __shfl_xor(b, off, 64);
    }
    if ((tid & 63) == 0) { wsum[tid >> 6] = a; wsum[4 + (tid >> 6)] = b; }
    __syncthreads();
    if (tid == 0) {
        float sa = wsum[0] + wsum[1] + wsum[2] + wsum[3];
        float sb = wsum[4] + wsum[5] + wsum[6] + wsum[7];
        out[0] = -sa;
        if (out_size > 1) out[1] = -0.5f * sb;   // LAMDA = 0.5
    }
}

extern "C" void kernel_launch(void* const* d_in, const int* in_sizes, int n_in,
                              void* d_out, int out_size, void* d_ws, size_t ws_size,
                              hipStream_t stream) {
    const float* feats   = (const float*)d_in[0];
    const float* centers = (const float*)d_in[1];
    const int*   labels  = (const int*)d_in[2];
    const int*   camids  = (const int*)d_in[3];
    float* out = (float*)d_out;

    __bf16* fnorm = (__bf16*)d_ws;
    float* d_acc  = (float*)((char*)d_ws + (size_t)N_SAMP * DIM * sizeof(__bf16));
    float* d_own  = d_acc + 8 * 2 * N_SAMP;

    norm_kernel<<<N_SAMP, 256, 0, stream>>>(feats, fnorm, d_acc);
    sims_kernel<<<NWG, 512, 0, stream>>>(fnorm, centers, labels, camids, d_acc, d_own);
    finalize_kernel<<<1, 256, 0, stream>>>(d_acc, d_own, labels, camids, out, out_size);
}